// Round 2
// baseline (427.266 us; speedup 1.0000x reference)
//
#include <hip/hip_runtime.h>
#include <hip/hip_bf16.h>
#include <math.h>

#define DIM 192
#define NB  16
#define NH  64
#define NW  64
#define NT  4096   // NH*NW

typedef __attribute__((ext_vector_type(8))) short short8;
typedef __attribute__((ext_vector_type(4))) float f32x4;
typedef __attribute__((address_space(3))) void* as3_void;
typedef const __attribute__((address_space(1))) void* as1_cvoid;

__device__ __forceinline__ unsigned short f2bf(float x) {
    unsigned int u = __float_as_uint(x);
    u = u + 0x7fffu + ((u >> 16) & 1u);
    return (unsigned short)(u >> 16);
}
__device__ __forceinline__ float bf2f(unsigned short h) {
    return __uint_as_float(((unsigned int)h) << 16);
}
__device__ __forceinline__ void gload16(const void* g, void* l) {
    __builtin_amdgcn_global_load_lds((as1_cvoid)g, (as3_void)l, 16, 0, 0);
}

// ---------------------------------------------------------------------------
// Kernel 1: prep. (a) fold alpha0*I + a1*w1 + a2*w3 + a3*w5 into one 5x5
// depthwise kernel per channel; (b) split Wk/Wv/Wr into bf16 hi/lo.
__global__ void k_prep(const float* __restrict__ w1, const float* __restrict__ w3,
                       const float* __restrict__ w5, const float* __restrict__ alpha,
                       const float* __restrict__ Wk, const float* __restrict__ Wv,
                       const float* __restrict__ Wr,
                       float* __restrict__ wc,
                       unsigned short* __restrict__ Whi,
                       unsigned short* __restrict__ Wlo) {
    int tid = threadIdx.x;
    if (tid < DIM) {
        int c = tid;
        float a0 = alpha[0], a1 = alpha[1], a2 = alpha[2], a3 = alpha[3];
        #pragma unroll
        for (int kh = 0; kh < 5; ++kh) {
            #pragma unroll
            for (int kw = 0; kw < 5; ++kw) {
                float v = a3 * w5[c * 25 + kh * 5 + kw];
                if (kh >= 1 && kh <= 3 && kw >= 1 && kw <= 3)
                    v += a2 * w3[c * 9 + (kh - 1) * 3 + (kw - 1)];
                if (kh == 2 && kw == 2)
                    v += a0 + a1 * w1[c];
                wc[c * 25 + kh * 5 + kw] = v;
            }
        }
    }
    for (int e = tid; e < 3 * DIM * DIM; e += 256) {
        int mat = e / (DIM * DIM);
        int idx = e - mat * DIM * DIM;
        const float* W = (mat == 0) ? Wk : (mat == 1 ? Wv : Wr);
        float v = W[idx];
        unsigned short h = f2bf(v);
        Whi[e] = h;
        Wlo[e] = f2bf(v - bf2f(h));
    }
}

// ---------------------------------------------------------------------------
// Kernel 2: depthwise 5x5 conv, sliding-column register window.
// Emits xs as split bf16 (hi, lo) for the MFMA GEMM.
__global__ __launch_bounds__(192) void k_conv(const float* __restrict__ x,
                                              const float* __restrict__ wc,
                                              unsigned short* __restrict__ xs_hi,
                                              unsigned short* __restrict__ xs_lo) {
    int c  = threadIdx.x;
    int bh = blockIdx.x;
    int b = bh >> 6, h = bh & 63;
    const float* xb = x + (size_t)b * NT * DIM + c;
    size_t obase = ((size_t)b * NT + (size_t)h * NW) * DIM + c;

    float wgt[25];
    #pragma unroll
    for (int j = 0; j < 25; ++j) wgt[j] = wc[c * 25 + j];

    const float* rowp[5];
    bool rok[5];
    #pragma unroll
    for (int dh = 0; dh < 5; ++dh) {
        int hh = h + dh - 2;
        rok[dh] = (hh >= 0 && hh < NH);
        rowp[dh] = xb + (size_t)(rok[dh] ? hh : 0) * NW * DIM;
    }

    float win[5][5];
    #pragma unroll
    for (int dh = 0; dh < 5; ++dh) {
        win[dh][0] = 0.f; win[dh][1] = 0.f; win[dh][2] = 0.f;
        win[dh][3] = rok[dh] ? rowp[dh][(size_t)0 * DIM] : 0.f;
        win[dh][4] = rok[dh] ? rowp[dh][(size_t)1 * DIM] : 0.f;
    }

    for (int w = 0; w < NW; ++w) {
        int wcol = w + 2;
        bool cok = (wcol < NW);
        #pragma unroll
        for (int dh = 0; dh < 5; ++dh) {
            win[dh][0] = win[dh][1];
            win[dh][1] = win[dh][2];
            win[dh][2] = win[dh][3];
            win[dh][3] = win[dh][4];
            win[dh][4] = (rok[dh] && cok) ? rowp[dh][(size_t)wcol * DIM] : 0.f;
        }
        float acc = 0.f;
        #pragma unroll
        for (int dh = 0; dh < 5; ++dh)
            #pragma unroll
            for (int dw = 0; dw < 5; ++dw)
                acc = fmaf(win[dh][dw], wgt[dh * 5 + dw], acc);
        unsigned short hb = f2bf(acc);
        xs_hi[obase + (size_t)w * DIM] = hb;
        xs_lo[obase + (size_t)w * DIM] = f2bf(acc - bf2f(hb));
    }
}

// ---------------------------------------------------------------------------
// Kernel 3: k/v/r projections via split-bf16 MFMA (hi*hi + hi*lo + lo*hi).
// Block tile 128(M) x 192(N=full mat), BK=32, 4 waves as 2x2.
// A = xs (M x K, k-contig), B = W (N x K, k-contig). Output transposed:
// Out[(b*DIM + n)*NT + t]. mat 2 gets sigmoid.
// LDS layout: [kgroup][row][8 bf16] -> granule index kg*ROWS+row, so staging
// dest is linear in thread id (global_load_lds wave-uniform-base + lane*16).
__global__ __launch_bounds__(256) void k_gemm_qkv_mfma(
        const unsigned short* __restrict__ xs_hi,
        const unsigned short* __restrict__ xs_lo,
        const unsigned short* __restrict__ Whi,
        const unsigned short* __restrict__ Wlo,
        float* __restrict__ kT, float* __restrict__ vT, float* __restrict__ srT) {
    __shared__ __align__(16) short As_hi[4][128][8];
    __shared__ __align__(16) short As_lo[4][128][8];
    __shared__ __align__(16) short Bs_hi[4][192][8];
    __shared__ __align__(16) short Bs_lo[4][192][8];

    const int tid  = threadIdx.x;
    const int lane = tid & 63;
    const int wid  = tid >> 6;
    const int wm = wid >> 1, wn = wid & 1;
    const int m0 = blockIdx.x * 128;
    const int mat = blockIdx.z;

    const unsigned short* Wh = Whi + mat * (DIM * DIM);
    const unsigned short* Wl = Wlo + mat * (DIM * DIM);
    float* Out = (mat == 0) ? kT : (mat == 1 ? vT : srT);

    f32x4 acc[4][6];
    #pragma unroll
    for (int i = 0; i < 4; ++i)
        #pragma unroll
        for (int j = 0; j < 6; ++j)
            acc[i][j] = (f32x4){0.f, 0.f, 0.f, 0.f};

    const int l15 = lane & 15;
    const int lkg = lane >> 4;

    for (int k0 = 0; k0 < DIM; k0 += 32) {
        // ---- stage: A hi/lo (2 rounds each), B hi/lo (3 rounds each) ----
        #pragma unroll
        for (int r = 0; r < 2; ++r) {
            int g = r * 256 + tid;
            int kg = g >> 7, row = g & 127;
            size_t src = (size_t)(m0 + row) * DIM + k0 + kg * 8;
            int doff = (r * 256 + wid * 64) * 16;
            gload16(xs_hi + src, (char*)&As_hi[0][0][0] + doff);
            gload16(xs_lo + src, (char*)&As_lo[0][0][0] + doff);
        }
        #pragma unroll
        for (int r = 0; r < 3; ++r) {
            int g = r * 256 + tid;
            int kg = g / 192, col = g - kg * 192;
            size_t src = (size_t)col * DIM + k0 + kg * 8;
            int doff = (r * 256 + wid * 64) * 16;
            gload16(Wh + src, (char*)&Bs_hi[0][0][0] + doff);
            gload16(Wl + src, (char*)&Bs_lo[0][0][0] + doff);
        }
        __syncthreads();

        short8 ah[4], al[4], bh[6], bl[6];
        #pragma unroll
        for (int mf = 0; mf < 4; ++mf) {
            int row = wm * 64 + mf * 16 + l15;
            ah[mf] = *(const short8*)&As_hi[lkg][row][0];
            al[mf] = *(const short8*)&As_lo[lkg][row][0];
        }
        #pragma unroll
        for (int nf = 0; nf < 6; ++nf) {
            int col = wn * 96 + nf * 16 + l15;
            bh[nf] = *(const short8*)&Bs_hi[lkg][col][0];
            bl[nf] = *(const short8*)&Bs_lo[lkg][col][0];
        }
        #pragma unroll
        for (int mf = 0; mf < 4; ++mf)
            #pragma unroll
            for (int nf = 0; nf < 6; ++nf) {
                acc[mf][nf] = __builtin_amdgcn_mfma_f32_16x16x32_bf16(ah[mf], bh[nf], acc[mf][nf], 0, 0, 0);
                acc[mf][nf] = __builtin_amdgcn_mfma_f32_16x16x32_bf16(ah[mf], bl[nf], acc[mf][nf], 0, 0, 0);
                acc[mf][nf] = __builtin_amdgcn_mfma_f32_16x16x32_bf16(al[mf], bh[nf], acc[mf][nf], 0, 0, 0);
            }
        __syncthreads();
    }

    const int b  = m0 >> 12;
    const int tb = m0 & 4095;
    #pragma unroll
    for (int mf = 0; mf < 4; ++mf) {
        int t = tb + wm * 64 + mf * 16 + (lane >> 4) * 4;
        #pragma unroll
        for (int nf = 0; nf < 6; ++nf) {
            int c = wn * 96 + nf * 16 + l15;
            f32x4 v = acc[mf][nf];
            if (mat == 2) {
                v.x = 1.0f / (1.0f + expf(-v.x));
                v.y = 1.0f / (1.0f + expf(-v.y));
                v.z = 1.0f / (1.0f + expf(-v.z));
                v.w = 1.0f / (1.0f + expf(-v.w));
            }
            *(f32x4*)&Out[((size_t)(b * DIM + c)) * NT + t] = v;
        }
    }
}

// ---------------------------------------------------------------------------
// Kernel 4: bidirectional WKV4 (unchanged). One block per (b,c).
__global__ __launch_bounds__(256) void k_wkv(
        const float* __restrict__ kT, const float* __restrict__ vT,
        const float* __restrict__ srT, const float* __restrict__ decay,
        const float* __restrict__ boost, float* __restrict__ zT) {
    __shared__ float sa[256], sb[256];
    int bc = blockIdx.x;
    int c = bc % DIM;
    size_t base = (size_t)bc * NT;
    int tid = threadIdx.x;
    int t0 = tid * 16;

    float w  = decay[c] * (1.0f / 4096.0f);
    float u  = boost[c] * (1.0f / 4096.0f);
    float ew = expf(-w);
    float eu = expf(u);

    float ek[16], ekv[16], vv[16];
    #pragma unroll
    for (int j = 0; j < 16; j += 4) {
        float4 k4 = *(const float4*)&kT[base + t0 + j];
        float4 v4 = *(const float4*)&vT[base + t0 + j];
        ek[j + 0] = expf(k4.x); ek[j + 1] = expf(k4.y);
        ek[j + 2] = expf(k4.z); ek[j + 3] = expf(k4.w);
        vv[j + 0] = v4.x; vv[j + 1] = v4.y; vv[j + 2] = v4.z; vv[j + 3] = v4.w;
        ekv[j + 0] = ek[j + 0] * v4.x; ekv[j + 1] = ek[j + 1] * v4.y;
        ekv[j + 2] = ek[j + 2] * v4.z; ekv[j + 3] = ek[j + 3] * v4.w;
    }

    float r = ew * ew; r = r * r; r = r * r; r = r * r;   // ew^16

    float La = 0.f, Lb = 0.f;
    #pragma unroll
    for (int j = 0; j < 16; ++j) { La = fmaf(ew, La, ekv[j]); Lb = fmaf(ew, Lb, ek[j]); }
    sa[tid] = La; sb[tid] = Lb;
    __syncthreads();
    float f = r;
    for (int d = 1; d < 256; d <<= 1) {
        float ta = (tid >= d) ? sa[tid - d] : 0.f;
        float tb_ = (tid >= d) ? sb[tid - d] : 0.f;
        __syncthreads();
        sa[tid] = fmaf(f, ta, sa[tid]);
        sb[tid] = fmaf(f, tb_, sb[tid]);
        __syncthreads();
        f = f * f;
    }
    float Ca = (tid > 0) ? sa[tid - 1] : 0.f;
    float Cb = (tid > 0) ? sb[tid - 1] : 0.f;
    __syncthreads();

    float Ra = 0.f, Rb = 0.f;
    #pragma unroll
    for (int j = 15; j >= 0; --j) { Ra = fmaf(ew, Ra, ekv[j]); Rb = fmaf(ew, Rb, ek[j]); }
    sa[255 - tid] = Ra; sb[255 - tid] = Rb;
    __syncthreads();
    f = r;
    for (int d = 1; d < 256; d <<= 1) {
        float ta = (tid >= d) ? sa[tid - d] : 0.f;
        float tb_ = (tid >= d) ? sb[tid - d] : 0.f;
        __syncthreads();
        sa[tid] = fmaf(f, ta, sa[tid]);
        sb[tid] = fmaf(f, tb_, sb[tid]);
        __syncthreads();
        f = f * f;
    }
    float Da = (tid < 255) ? sa[254 - tid] : 0.f;
    float Db = (tid < 255) ? sb[254 - tid] : 0.f;

    float ab[16], bb[16];
    {
        float a = Da, bv = Db;
        #pragma unroll
        for (int j = 15; j >= 0; --j) {
            ab[j] = a; bb[j] = bv;
            a  = fmaf(ew, a, ekv[j]);
            bv = fmaf(ew, bv, ek[j]);
        }
    }
    float outv[16];
    {
        float a = Ca, bv = Cb;
        #pragma unroll
        for (int j = 0; j < 16; ++j) {
            float af = a, bf = bv;
            a  = fmaf(ew, a, ekv[j]);
            bv = fmaf(ew, bv, ek[j]);
            float euk = eu * ek[j];
            float num = af + ab[j] + euk * vv[j];
            float den = bf + bb[j] + euk;
            outv[j] = num / den;
        }
    }
    #pragma unroll
    for (int j = 0; j < 16; j += 4) {
        float4 s4 = *(const float4*)&srT[base + t0 + j];
        float4 o;
        o.x = s4.x * outv[j + 0];
        o.y = s4.y * outv[j + 1];
        o.z = s4.z * outv[j + 2];
        o.w = s4.w * outv[j + 3];
        *(float4*)&zT[base + t0 + j] = o;
    }
}

// ---------------------------------------------------------------------------
// Kernel 5: output projection (fp32 VALU, unchanged). A = zT (B,C,T) k-major.
#define MT 128
#define NT_ 64
#define KT 32
#define LDA 132
#define LDB 68

__global__ __launch_bounds__(256) void k_gemm_out(
        const float* __restrict__ zT, const float* __restrict__ Wo,
        float* __restrict__ out) {
    __shared__ float As[KT][LDA];
    __shared__ float Bs[KT][LDB];
    int tid = threadIdx.x;
    int m0 = blockIdx.x * MT;
    int n0 = blockIdx.y * NT_;
    int b  = m0 >> 12;
    int t0 = m0 & 4095;

    float acc[8][4];
    #pragma unroll
    for (int i = 0; i < 8; ++i)
        #pragma unroll
        for (int j = 0; j < 4; ++j) acc[i][j] = 0.f;

    int a_kk = tid >> 5;
    int a_c4 = (tid & 31) * 4;
    int b_n  = tid >> 3;
    int b_k4 = (tid & 7) * 4;
    int tmy = (tid >> 4) * 8;
    int tnx = (tid & 15) * 4;

    for (int k0 = 0; k0 < DIM; k0 += KT) {
        #pragma unroll
        for (int r = 0; r < 4; ++r) {
            int kk = a_kk + r * 8;
            float4 v = *(const float4*)&zT[((size_t)(b * DIM + k0 + kk)) * NT + t0 + a_c4];
            *(float4*)&As[kk][a_c4] = v;
        }
        #pragma unroll
        for (int r = 0; r < 2; ++r) {
            int nn = b_n + r * 32;
            float4 v = *(const float4*)&Wo[(size_t)(n0 + nn) * DIM + k0 + b_k4];
            Bs[b_k4 + 0][nn] = v.x; Bs[b_k4 + 1][nn] = v.y;
            Bs[b_k4 + 2][nn] = v.z; Bs[b_k4 + 3][nn] = v.w;
        }
        __syncthreads();
        #pragma unroll
        for (int kk = 0; kk < KT; ++kk) {
            float4 a0 = *(const float4*)&As[kk][tmy];
            float4 a1 = *(const float4*)&As[kk][tmy + 4];
            float4 b0 = *(const float4*)&Bs[kk][tnx];
            float av[8] = {a0.x, a0.y, a0.z, a0.w, a1.x, a1.y, a1.z, a1.w};
            float bv[4] = {b0.x, b0.y, b0.z, b0.w};
            #pragma unroll
            for (int i = 0; i < 8; ++i)
                #pragma unroll
                for (int j = 0; j < 4; ++j)
                    acc[i][j] = fmaf(av[i], bv[j], acc[i][j]);
        }
        __syncthreads();
    }

    #pragma unroll
    for (int i = 0; i < 8; ++i) {
        size_t rowbase = (size_t)(m0 + tmy + i) * DIM + n0 + tnx;
        *(float4*)&out[rowbase] = make_float4(acc[i][0], acc[i][1], acc[i][2], acc[i][3]);
    }
}

// ---------------------------------------------------------------------------
extern "C" void kernel_launch(void* const* d_in, const int* in_sizes, int n_in,
                              void* d_out, int out_size, void* d_ws, size_t ws_size,
                              hipStream_t stream) {
    const float* x     = (const float*)d_in[0];
    const float* w1    = (const float*)d_in[1];
    const float* w3    = (const float*)d_in[2];
    const float* w5    = (const float*)d_in[3];
    const float* alpha = (const float*)d_in[4];
    const float* Wk    = (const float*)d_in[5];
    const float* Wv    = (const float*)d_in[6];
    const float* Wr    = (const float*)d_in[7];
    const float* Wo    = (const float*)d_in[8];
    const float* decay = (const float*)d_in[9];
    const float* boost = (const float*)d_in[10];
    float* out = (float*)d_out;
    float* ws  = (float*)d_ws;

    const size_t BIG = (size_t)NB * NT * DIM;   // 12,582,912 elements

    float* wc = ws;                                        // 4800 floats
    unsigned short* Whi = (unsigned short*)(ws + 8192);    // 110592 ushorts
    unsigned short* Wlo = (unsigned short*)(ws + 63488);   // 110592 ushorts
    unsigned short* xs_hi = (unsigned short*)(ws + 118784);   // BIG ushorts
    unsigned short* xs_lo = xs_hi + BIG;                      // BIG ushorts
    float* kT  = ws + 12701696;                               // BIG floats
    float* vT  = kT + BIG;
    float* srT = vT + BIG;
    float* zT  = ws + 118784;   // fp32, overlays xs_hi/xs_lo (dead after qkv)

    hipLaunchKernelGGL(k_prep, dim3(1), dim3(256), 0, stream,
                       w1, w3, w5, alpha, Wk, Wv, Wr, wc, Whi, Wlo);
    hipLaunchKernelGGL(k_conv, dim3(NB * NH), dim3(DIM), 0, stream,
                       x, wc, xs_hi, xs_lo);
    hipLaunchKernelGGL(k_gemm_qkv_mfma, dim3(65536 / 128, 1, 3), dim3(256), 0, stream,
                       xs_hi, xs_lo, Whi, Wlo, kT, vT, srT);
    hipLaunchKernelGGL(k_wkv, dim3(NB * DIM), dim3(256), 0, stream,
                       kT, vT, srT, decay, boost, zT);
    hipLaunchKernelGGL(k_gemm_out, dim3(65536 / MT, DIM / NT_), dim3(256), 0, stream,
                       zT, Wo, out);
}

// Round 3
// 344.380 us; speedup vs baseline: 1.2407x; 1.2407x over previous
//
#include <hip/hip_runtime.h>
#include <hip/hip_bf16.h>
#include <math.h>

#define DIM 192
#define NB  16
#define NH  64
#define NW  64
#define NT  4096   // NH*NW

typedef __attribute__((ext_vector_type(8))) short short8;
typedef __attribute__((ext_vector_type(4))) float f32x4;

__device__ __forceinline__ unsigned short f2bf(float x) {
    unsigned int u = __float_as_uint(x);
    u = u + 0x7fffu + ((u >> 16) & 1u);
    return (unsigned short)(u >> 16);
}
__device__ __forceinline__ float bf2f(unsigned short h) {
    return __uint_as_float(((unsigned int)h) << 16);
}

// ---------------------------------------------------------------------------
// Kernel 1: prep (parallel). Block 0: fold the three depthwise kernels into
// one 5x5 per channel. Blocks 1..432: split Wk/Wv/Wr into bf16 hi/lo.
__global__ void k_prep(const float* __restrict__ w1, const float* __restrict__ w3,
                       const float* __restrict__ w5, const float* __restrict__ alpha,
                       const float* __restrict__ Wk, const float* __restrict__ Wv,
                       const float* __restrict__ Wr,
                       float* __restrict__ wc,
                       unsigned short* __restrict__ Whi,
                       unsigned short* __restrict__ Wlo) {
    int bid = blockIdx.x, tid = threadIdx.x;
    if (bid == 0) {
        if (tid < DIM) {
            int c = tid;
            float a0 = alpha[0], a1 = alpha[1], a2 = alpha[2], a3 = alpha[3];
            #pragma unroll
            for (int kh = 0; kh < 5; ++kh)
                #pragma unroll
                for (int kw = 0; kw < 5; ++kw) {
                    float v = a3 * w5[c * 25 + kh * 5 + kw];
                    if (kh >= 1 && kh <= 3 && kw >= 1 && kw <= 3)
                        v += a2 * w3[c * 9 + (kh - 1) * 3 + (kw - 1)];
                    if (kh == 2 && kw == 2)
                        v += a0 + a1 * w1[c];
                    wc[c * 25 + kh * 5 + kw] = v;
                }
        }
        return;
    }
    int e = (bid - 1) * 256 + tid;           // 432 blocks cover 3*192*192
    if (e >= 3 * DIM * DIM) return;
    int mat = e / (DIM * DIM);
    int idx = e - mat * DIM * DIM;
    const float* W = (mat == 0) ? Wk : (mat == 1 ? Wv : Wr);
    float v = W[idx];
    unsigned short h = f2bf(v);
    Whi[e] = h;
    Wlo[e] = f2bf(v - bf2f(h));
}

// ---------------------------------------------------------------------------
// Kernel 2: depthwise 5x5 conv, sliding-column register window.
// Emits xs split into bf16 hi/lo, row-major [t][c] (c contiguous).
__global__ __launch_bounds__(192) void k_conv(const float* __restrict__ x,
                                              const float* __restrict__ wc,
                                              unsigned short* __restrict__ xs_hi,
                                              unsigned short* __restrict__ xs_lo) {
    int c  = threadIdx.x;
    int bh = blockIdx.x;
    int b = bh >> 6, h = bh & 63;
    const float* xb = x + (size_t)b * NT * DIM + c;
    size_t obase = ((size_t)b * NT + (size_t)h * NW) * DIM + c;

    float wgt[25];
    #pragma unroll
    for (int j = 0; j < 25; ++j) wgt[j] = wc[c * 25 + j];

    const float* rowp[5];
    bool rok[5];
    #pragma unroll
    for (int dh = 0; dh < 5; ++dh) {
        int hh = h + dh - 2;
        rok[dh] = (hh >= 0 && hh < NH);
        rowp[dh] = xb + (size_t)(rok[dh] ? hh : 0) * NW * DIM;
    }

    float win[5][5];
    #pragma unroll
    for (int dh = 0; dh < 5; ++dh) {
        win[dh][0] = 0.f; win[dh][1] = 0.f; win[dh][2] = 0.f;
        win[dh][3] = rok[dh] ? rowp[dh][(size_t)0 * DIM] : 0.f;
        win[dh][4] = rok[dh] ? rowp[dh][(size_t)1 * DIM] : 0.f;
    }

    for (int w = 0; w < NW; ++w) {
        int wcol = w + 2;
        bool cok = (wcol < NW);
        #pragma unroll
        for (int dh = 0; dh < 5; ++dh) {
            win[dh][0] = win[dh][1];
            win[dh][1] = win[dh][2];
            win[dh][2] = win[dh][3];
            win[dh][3] = win[dh][4];
            win[dh][4] = (rok[dh] && cok) ? rowp[dh][(size_t)wcol * DIM] : 0.f;
        }
        float acc = 0.f;
        #pragma unroll
        for (int dh = 0; dh < 5; ++dh)
            #pragma unroll
            for (int dw = 0; dw < 5; ++dw)
                acc = fmaf(win[dh][dw], wgt[dh * 5 + dw], acc);
        unsigned short hb = f2bf(acc);
        xs_hi[obase + (size_t)w * DIM] = hb;
        xs_lo[obase + (size_t)w * DIM] = f2bf(acc - bf2f(hb));
    }
}

// ---------------------------------------------------------------------------
// Kernel 3: k/v/r projections, LDS-free direct-fragment MFMA.
// A-fragment of mfma_f32_16x16x32_bf16: lane holds row (l&15), 8 contiguous k
// at (l>>4)*8 -> one 16B global load per fragment from row-major xs [t][c].
// 6 waves/block as 2m x 3n; wave tile 32(m) x 64(n): mf=2, nf=4.
// Block tile 64(m) x 192(n=full). No LDS, no barriers. 3-term split product.
// Output transposed: Out[(b*DIM + n)*NT + t]; mat 2 gets sigmoid.
#define LOADSET(AH, AL, BH, BL, K0)                                          \
    {                                                                        \
        _Pragma("unroll")                                                    \
        for (int mf = 0; mf < 2; ++mf) {                                     \
            size_t a = (size_t)(arow + mf * 16) * DIM + (K0) + kofs;         \
            AH[mf] = *(const short8*)&xs_hi[a];                              \
            AL[mf] = *(const short8*)&xs_lo[a];                              \
        }                                                                    \
        _Pragma("unroll")                                                    \
        for (int nf = 0; nf < 4; ++nf) {                                     \
            size_t bb = (size_t)(bcol + nf * 16) * DIM + (K0) + kofs;        \
            BH[nf] = *(const short8*)&Wh[bb];                                \
            BL[nf] = *(const short8*)&Wl[bb];                                \
        }                                                                    \
    }

#define MFMASET(AH, AL, BH, BL)                                              \
    {                                                                        \
        _Pragma("unroll")                                                    \
        for (int mf = 0; mf < 2; ++mf)                                       \
            _Pragma("unroll")                                                \
            for (int nf = 0; nf < 4; ++nf) {                                 \
                acc[mf][nf] = __builtin_amdgcn_mfma_f32_16x16x32_bf16(       \
                    AH[mf], BH[nf], acc[mf][nf], 0, 0, 0);                   \
                acc[mf][nf] = __builtin_amdgcn_mfma_f32_16x16x32_bf16(       \
                    AH[mf], BL[nf], acc[mf][nf], 0, 0, 0);                   \
                acc[mf][nf] = __builtin_amdgcn_mfma_f32_16x16x32_bf16(       \
                    AL[mf], BH[nf], acc[mf][nf], 0, 0, 0);                   \
            }                                                                \
    }

__global__ __launch_bounds__(384, 3) void k_gemm_qkv_direct(
        const unsigned short* __restrict__ xs_hi,
        const unsigned short* __restrict__ xs_lo,
        const unsigned short* __restrict__ Whi,
        const unsigned short* __restrict__ Wlo,
        float* __restrict__ kT, float* __restrict__ vT, float* __restrict__ srT) {
    const int tid  = threadIdx.x;
    const int lane = tid & 63;
    const int wid  = tid >> 6;          // 0..5
    const int wn = wid % 3;             // n-wave: 0..2 (64 cols each)
    const int wm = wid / 3;             // m-wave: 0..1 (32 rows each)
    const int l15  = lane & 15;
    const int kofs = (lane >> 4) * 8;
    const int mat = blockIdx.y;

    const unsigned short* Wh = Whi + mat * (DIM * DIM);
    const unsigned short* Wl = Wlo + mat * (DIM * DIM);
    float* Out = (mat == 0) ? kT : (mat == 1 ? vT : srT);

    const int mbase = blockIdx.x * 64 + wm * 32;
    const int arow  = mbase + l15;      // global A row for this lane
    const int bcol  = wn * 64 + l15;    // W row (= output channel) for this lane

    f32x4 acc[2][4];
    #pragma unroll
    for (int i = 0; i < 2; ++i)
        #pragma unroll
        for (int j = 0; j < 4; ++j)
            acc[i][j] = (f32x4){0.f, 0.f, 0.f, 0.f};

    short8 ah0[2], al0[2], bh0[4], bl0[4];
    short8 ah1[2], al1[2], bh1[4], bl1[4];

    // 1-deep software pipeline over the 6 K-chunks (K=192, 32 per chunk)
    LOADSET(ah0, al0, bh0, bl0, 0)
    LOADSET(ah1, al1, bh1, bl1, 32)
    MFMASET(ah0, al0, bh0, bl0)
    LOADSET(ah0, al0, bh0, bl0, 64)
    MFMASET(ah1, al1, bh1, bl1)
    LOADSET(ah1, al1, bh1, bl1, 96)
    MFMASET(ah0, al0, bh0, bl0)
    LOADSET(ah0, al0, bh0, bl0, 128)
    MFMASET(ah1, al1, bh1, bl1)
    LOADSET(ah1, al1, bh1, bl1, 160)
    MFMASET(ah0, al0, bh0, bl0)
    MFMASET(ah1, al1, bh1, bl1)

    const int b  = mbase >> 12;
    const int tb = (mbase & 4095) + (lane >> 4) * 4;
    #pragma unroll
    for (int mf = 0; mf < 2; ++mf) {
        int t = tb + mf * 16;
        #pragma unroll
        for (int nf = 0; nf < 4; ++nf) {
            int c = wn * 64 + nf * 16 + l15;
            f32x4 v = acc[mf][nf];
            if (mat == 2) {
                v.x = 1.0f / (1.0f + expf(-v.x));
                v.y = 1.0f / (1.0f + expf(-v.y));
                v.z = 1.0f / (1.0f + expf(-v.z));
                v.w = 1.0f / (1.0f + expf(-v.w));
            }
            *(f32x4*)&Out[((size_t)(b * DIM + c)) * NT + t] = v;
        }
    }
}

// ---------------------------------------------------------------------------
// Kernel 4: bidirectional WKV4 (unchanged). One block per (b,c).
__global__ __launch_bounds__(256) void k_wkv(
        const float* __restrict__ kT, const float* __restrict__ vT,
        const float* __restrict__ srT, const float* __restrict__ decay,
        const float* __restrict__ boost, float* __restrict__ zT) {
    __shared__ float sa[256], sb[256];
    int bc = blockIdx.x;
    int c = bc % DIM;
    size_t base = (size_t)bc * NT;
    int tid = threadIdx.x;
    int t0 = tid * 16;

    float w  = decay[c] * (1.0f / 4096.0f);
    float u  = boost[c] * (1.0f / 4096.0f);
    float ew = expf(-w);
    float eu = expf(u);

    float ek[16], ekv[16], vv[16];
    #pragma unroll
    for (int j = 0; j < 16; j += 4) {
        float4 k4 = *(const float4*)&kT[base + t0 + j];
        float4 v4 = *(const float4*)&vT[base + t0 + j];
        ek[j + 0] = expf(k4.x); ek[j + 1] = expf(k4.y);
        ek[j + 2] = expf(k4.z); ek[j + 3] = expf(k4.w);
        vv[j + 0] = v4.x; vv[j + 1] = v4.y; vv[j + 2] = v4.z; vv[j + 3] = v4.w;
        ekv[j + 0] = ek[j + 0] * v4.x; ekv[j + 1] = ek[j + 1] * v4.y;
        ekv[j + 2] = ek[j + 2] * v4.z; ekv[j + 3] = ek[j + 3] * v4.w;
    }

    float r = ew * ew; r = r * r; r = r * r; r = r * r;   // ew^16

    float La = 0.f, Lb = 0.f;
    #pragma unroll
    for (int j = 0; j < 16; ++j) { La = fmaf(ew, La, ekv[j]); Lb = fmaf(ew, Lb, ek[j]); }
    sa[tid] = La; sb[tid] = Lb;
    __syncthreads();
    float f = r;
    for (int d = 1; d < 256; d <<= 1) {
        float ta = (tid >= d) ? sa[tid - d] : 0.f;
        float tb_ = (tid >= d) ? sb[tid - d] : 0.f;
        __syncthreads();
        sa[tid] = fmaf(f, ta, sa[tid]);
        sb[tid] = fmaf(f, tb_, sb[tid]);
        __syncthreads();
        f = f * f;
    }
    float Ca = (tid > 0) ? sa[tid - 1] : 0.f;
    float Cb = (tid > 0) ? sb[tid - 1] : 0.f;
    __syncthreads();

    float Ra = 0.f, Rb = 0.f;
    #pragma unroll
    for (int j = 15; j >= 0; --j) { Ra = fmaf(ew, Ra, ekv[j]); Rb = fmaf(ew, Rb, ek[j]); }
    sa[255 - tid] = Ra; sb[255 - tid] = Rb;
    __syncthreads();
    f = r;
    for (int d = 1; d < 256; d <<= 1) {
        float ta = (tid >= d) ? sa[tid - d] : 0.f;
        float tb_ = (tid >= d) ? sb[tid - d] : 0.f;
        __syncthreads();
        sa[tid] = fmaf(f, ta, sa[tid]);
        sb[tid] = fmaf(f, tb_, sb[tid]);
        __syncthreads();
        f = f * f;
    }
    float Da = (tid < 255) ? sa[254 - tid] : 0.f;
    float Db = (tid < 255) ? sb[254 - tid] : 0.f;

    float ab[16], bb[16];
    {
        float a = Da, bv = Db;
        #pragma unroll
        for (int j = 15; j >= 0; --j) {
            ab[j] = a; bb[j] = bv;
            a  = fmaf(ew, a, ekv[j]);
            bv = fmaf(ew, bv, ek[j]);
        }
    }
    float outv[16];
    {
        float a = Ca, bv = Cb;
        #pragma unroll
        for (int j = 0; j < 16; ++j) {
            float af = a, bf = bv;
            a  = fmaf(ew, a, ekv[j]);
            bv = fmaf(ew, bv, ek[j]);
            float euk = eu * ek[j];
            float num = af + ab[j] + euk * vv[j];
            float den = bf + bb[j] + euk;
            outv[j] = num / den;
        }
    }
    #pragma unroll
    for (int j = 0; j < 16; j += 4) {
        float4 s4 = *(const float4*)&srT[base + t0 + j];
        float4 o;
        o.x = s4.x * outv[j + 0];
        o.y = s4.y * outv[j + 1];
        o.z = s4.z * outv[j + 2];
        o.w = s4.w * outv[j + 3];
        *(float4*)&zT[base + t0 + j] = o;
    }
}

// ---------------------------------------------------------------------------
// Kernel 5: output projection (fp32 VALU, unchanged). A = zT (B,C,T) k-major.
#define MT 128
#define NT_ 64
#define KT 32
#define LDA 132
#define LDB 68

__global__ __launch_bounds__(256) void k_gemm_out(
        const float* __restrict__ zT, const float* __restrict__ Wo,
        float* __restrict__ out) {
    __shared__ float As[KT][LDA];
    __shared__ float Bs[KT][LDB];
    int tid = threadIdx.x;
    int m0 = blockIdx.x * MT;
    int n0 = blockIdx.y * NT_;
    int b  = m0 >> 12;
    int t0 = m0 & 4095;

    float acc[8][4];
    #pragma unroll
    for (int i = 0; i < 8; ++i)
        #pragma unroll
        for (int j = 0; j < 4; ++j) acc[i][j] = 0.f;

    int a_kk = tid >> 5;
    int a_c4 = (tid & 31) * 4;
    int b_n  = tid >> 3;
    int b_k4 = (tid & 7) * 4;
    int tmy = (tid >> 4) * 8;
    int tnx = (tid & 15) * 4;

    for (int k0 = 0; k0 < DIM; k0 += KT) {
        #pragma unroll
        for (int r = 0; r < 4; ++r) {
            int kk = a_kk + r * 8;
            float4 v = *(const float4*)&zT[((size_t)(b * DIM + k0 + kk)) * NT + t0 + a_c4];
            *(float4*)&As[kk][a_c4] = v;
        }
        #pragma unroll
        for (int r = 0; r < 2; ++r) {
            int nn = b_n + r * 32;
            float4 v = *(const float4*)&Wo[(size_t)(n0 + nn) * DIM + k0 + b_k4];
            Bs[b_k4 + 0][nn] = v.x; Bs[b_k4 + 1][nn] = v.y;
            Bs[b_k4 + 2][nn] = v.z; Bs[b_k4 + 3][nn] = v.w;
        }
        __syncthreads();
        #pragma unroll
        for (int kk = 0; kk < KT; ++kk) {
            float4 a0 = *(const float4*)&As[kk][tmy];
            float4 a1 = *(const float4*)&As[kk][tmy + 4];
            float4 b0 = *(const float4*)&Bs[kk][tnx];
            float av[8] = {a0.x, a0.y, a0.z, a0.w, a1.x, a1.y, a1.z, a1.w};
            float bv[4] = {b0.x, b0.y, b0.z, b0.w};
            #pragma unroll
            for (int i = 0; i < 8; ++i)
                #pragma unroll
                for (int j = 0; j < 4; ++j)
                    acc[i][j] = fmaf(av[i], bv[j], acc[i][j]);
        }
        __syncthreads();
    }

    #pragma unroll
    for (int i = 0; i < 8; ++i) {
        size_t rowbase = (size_t)(m0 + tmy + i) * DIM + n0 + tnx;
        *(float4*)&out[rowbase] = make_float4(acc[i][0], acc[i][1], acc[i][2], acc[i][3]);
    }
}

// ---------------------------------------------------------------------------
extern "C" void kernel_launch(void* const* d_in, const int* in_sizes, int n_in,
                              void* d_out, int out_size, void* d_ws, size_t ws_size,
                              hipStream_t stream) {
    const float* x     = (const float*)d_in[0];
    const float* w1    = (const float*)d_in[1];
    const float* w3    = (const float*)d_in[2];
    const float* w5    = (const float*)d_in[3];
    const float* alpha = (const float*)d_in[4];
    const float* Wk    = (const float*)d_in[5];
    const float* Wv    = (const float*)d_in[6];
    const float* Wr    = (const float*)d_in[7];
    const float* Wo    = (const float*)d_in[8];
    const float* decay = (const float*)d_in[9];
    const float* boost = (const float*)d_in[10];
    float* out = (float*)d_out;
    float* ws  = (float*)d_ws;

    const size_t BIG = (size_t)NB * NT * DIM;   // 12,582,912 elements

    float* wc = ws;                                        // 4800 floats
    unsigned short* Whi = (unsigned short*)(ws + 8192);    // 110592 ushorts
    unsigned short* Wlo = (unsigned short*)(ws + 63488);   // 110592 ushorts
    unsigned short* xs_hi = (unsigned short*)(ws + 118784);   // BIG ushorts
    unsigned short* xs_lo = xs_hi + BIG;                      // BIG ushorts
    float* kT  = ws + 12701696;                               // BIG floats
    float* vT  = kT + BIG;
    float* srT = vT + BIG;
    float* zT  = ws + 118784;   // fp32, overlays xs_hi/xs_lo (dead after qkv)

    hipLaunchKernelGGL(k_prep, dim3(433), dim3(256), 0, stream,
                       w1, w3, w5, alpha, Wk, Wv, Wr, wc, Whi, Wlo);
    hipLaunchKernelGGL(k_conv, dim3(NB * NH), dim3(DIM), 0, stream,
                       x, wc, xs_hi, xs_lo);
    hipLaunchKernelGGL(k_gemm_qkv_direct, dim3(65536 / 64, 3), dim3(384), 0, stream,
                       xs_hi, xs_lo, Whi, Wlo, kT, vT, srT);
    hipLaunchKernelGGL(k_wkv, dim3(NB * DIM), dim3(256), 0, stream,
                       kT, vT, srT, decay, boost, zT);
    hipLaunchKernelGGL(k_gemm_out, dim3(65536 / MT, DIM / NT_), dim3(256), 0, stream,
                       zT, Wo, out);
}

// Round 4
// 300.263 us; speedup vs baseline: 1.4230x; 1.1469x over previous
//
#include <hip/hip_runtime.h>
#include <hip/hip_bf16.h>
#include <math.h>

#define DIM 192
#define NB  16
#define NH  64
#define NW  64
#define NT  4096   // NH*NW

#define BN   48    // qkv block N-tile (cols of W per block)
#define NKG  24    // 192/8 k-granules

typedef __attribute__((ext_vector_type(8))) short short8;
typedef __attribute__((ext_vector_type(4))) float f32x4;
typedef __attribute__((address_space(3))) void* as3_void;
typedef const __attribute__((address_space(1))) void* as1_cvoid;

__device__ __forceinline__ unsigned short f2bf(float x) {
    unsigned int u = __float_as_uint(x);
    u = u + 0x7fffu + ((u >> 16) & 1u);
    return (unsigned short)(u >> 16);
}
__device__ __forceinline__ float bf2f(unsigned short h) {
    return __uint_as_float(((unsigned int)h) << 16);
}
__device__ __forceinline__ void gload16(const void* g, void* l) {
    __builtin_amdgcn_global_load_lds((as1_cvoid)g, (as3_void)l, 16, 0, 0);
}

// ---------------------------------------------------------------------------
// Kernel 1: prep (parallel). Block 0: fold the three depthwise kernels into
// one 5x5 per channel. Blocks 1..432: split Wk/Wv/Wr into bf16 hi/lo.
__global__ void k_prep(const float* __restrict__ w1, const float* __restrict__ w3,
                       const float* __restrict__ w5, const float* __restrict__ alpha,
                       const float* __restrict__ Wk, const float* __restrict__ Wv,
                       const float* __restrict__ Wr,
                       float* __restrict__ wc,
                       unsigned short* __restrict__ Whi,
                       unsigned short* __restrict__ Wlo) {
    int bid = blockIdx.x, tid = threadIdx.x;
    if (bid == 0) {
        if (tid < DIM) {
            int c = tid;
            float a0 = alpha[0], a1 = alpha[1], a2 = alpha[2], a3 = alpha[3];
            #pragma unroll
            for (int kh = 0; kh < 5; ++kh)
                #pragma unroll
                for (int kw = 0; kw < 5; ++kw) {
                    float v = a3 * w5[c * 25 + kh * 5 + kw];
                    if (kh >= 1 && kh <= 3 && kw >= 1 && kw <= 3)
                        v += a2 * w3[c * 9 + (kh - 1) * 3 + (kw - 1)];
                    if (kh == 2 && kw == 2)
                        v += a0 + a1 * w1[c];
                    wc[c * 25 + kh * 5 + kw] = v;
                }
        }
        return;
    }
    int e = (bid - 1) * 256 + tid;
    if (e >= 3 * DIM * DIM) return;
    int mat = e / (DIM * DIM);
    int idx = e - mat * DIM * DIM;
    const float* W = (mat == 0) ? Wk : (mat == 1 ? Wv : Wr);
    float v = W[idx];
    unsigned short h = f2bf(v);
    Whi[e] = h;
    Wlo[e] = f2bf(v - bf2f(h));
}

// ---------------------------------------------------------------------------
// Kernel 2: depthwise 5x5 conv, sliding-column register window.
// Emits xs split into bf16 hi/lo, row-major [t][c] (c contiguous).
__global__ __launch_bounds__(192) void k_conv(const float* __restrict__ x,
                                              const float* __restrict__ wc,
                                              unsigned short* __restrict__ xs_hi,
                                              unsigned short* __restrict__ xs_lo) {
    int c  = threadIdx.x;
    int bh = blockIdx.x;
    int b = bh >> 6, h = bh & 63;
    const float* xb = x + (size_t)b * NT * DIM + c;
    size_t obase = ((size_t)b * NT + (size_t)h * NW) * DIM + c;

    float wgt[25];
    #pragma unroll
    for (int j = 0; j < 25; ++j) wgt[j] = wc[c * 25 + j];

    const float* rowp[5];
    bool rok[5];
    #pragma unroll
    for (int dh = 0; dh < 5; ++dh) {
        int hh = h + dh - 2;
        rok[dh] = (hh >= 0 && hh < NH);
        rowp[dh] = xb + (size_t)(rok[dh] ? hh : 0) * NW * DIM;
    }

    float win[5][5];
    #pragma unroll
    for (int dh = 0; dh < 5; ++dh) {
        win[dh][0] = 0.f; win[dh][1] = 0.f; win[dh][2] = 0.f;
        win[dh][3] = rok[dh] ? rowp[dh][(size_t)0 * DIM] : 0.f;
        win[dh][4] = rok[dh] ? rowp[dh][(size_t)1 * DIM] : 0.f;
    }

    for (int w = 0; w < NW; ++w) {
        int wcol = w + 2;
        bool cok = (wcol < NW);
        #pragma unroll
        for (int dh = 0; dh < 5; ++dh) {
            win[dh][0] = win[dh][1];
            win[dh][1] = win[dh][2];
            win[dh][2] = win[dh][3];
            win[dh][3] = win[dh][4];
            win[dh][4] = (rok[dh] && cok) ? rowp[dh][(size_t)wcol * DIM] : 0.f;
        }
        float acc = 0.f;
        #pragma unroll
        for (int dh = 0; dh < 5; ++dh)
            #pragma unroll
            for (int dw = 0; dw < 5; ++dw)
                acc = fmaf(win[dh][dw], wgt[dh * 5 + dw], acc);
        unsigned short hb = f2bf(acc);
        xs_hi[obase + (size_t)w * DIM] = hb;
        xs_lo[obase + (size_t)w * DIM] = f2bf(acc - bf2f(hb));
    }
}

// ---------------------------------------------------------------------------
// Kernel 3: k/v/r projections — W-stationary LDS + direct-global A fragments.
// Block: 256 threads (4 waves), tile 256(m) x 48(n). Wave tile 64m x 48n:
// mf=4, nf=3. W hi/lo (48x192) staged ONCE into LDS (36.9 KB), zero barriers
// in the main loop. A fragments are 16B contiguous global loads (row-major
// xs [t][c]). 2-deep named double-buffers for A (global) and B (LDS), full
// K unroll (6 chunks of 32), sched_barrier fences to pin the pipeline.
// 3-term split product: hi*hi + hi*lo + lo*hi. Output Out[(b*DIM+n)*NT+t].

#define LOADA(AH, AL, KC)                                                    \
    {                                                                        \
        _Pragma("unroll")                                                    \
        for (int mf = 0; mf < 4; ++mf) {                                     \
            size_t a = (size_t)(arow + mf * 16) * DIM + (KC) * 32 + kofs;    \
            AH[mf] = *(const short8*)&xs_hi[a];                              \
            AL[mf] = *(const short8*)&xs_lo[a];                              \
        }                                                                    \
    }

#define LOADB(BH, BL, KC)                                                    \
    {                                                                        \
        _Pragma("unroll")                                                    \
        for (int nf = 0; nf < 3; ++nf) {                                     \
            BH[nf] = *(const short8*)&Bs[0][(KC) * 4 + lkg][nf * 16 + l15][0]; \
            BL[nf] = *(const short8*)&Bs[1][(KC) * 4 + lkg][nf * 16 + l15][0]; \
        }                                                                    \
    }

#define COMP(AH, AL, BH, BL)                                                 \
    {                                                                        \
        _Pragma("unroll")                                                    \
        for (int mf = 0; mf < 4; ++mf)                                       \
            _Pragma("unroll")                                                \
            for (int nf = 0; nf < 3; ++nf)                                   \
                acc[mf][nf] = __builtin_amdgcn_mfma_f32_16x16x32_bf16(       \
                    AH[mf], BH[nf], acc[mf][nf], 0, 0, 0);                   \
        _Pragma("unroll")                                                    \
        for (int mf = 0; mf < 4; ++mf)                                       \
            _Pragma("unroll")                                                \
            for (int nf = 0; nf < 3; ++nf)                                   \
                acc[mf][nf] = __builtin_amdgcn_mfma_f32_16x16x32_bf16(       \
                    AH[mf], BL[nf], acc[mf][nf], 0, 0, 0);                   \
        _Pragma("unroll")                                                    \
        for (int mf = 0; mf < 4; ++mf)                                       \
            _Pragma("unroll")                                                \
            for (int nf = 0; nf < 3; ++nf)                                   \
                acc[mf][nf] = __builtin_amdgcn_mfma_f32_16x16x32_bf16(       \
                    AL[mf], BH[nf], acc[mf][nf], 0, 0, 0);                   \
    }

#define FENCE __builtin_amdgcn_sched_barrier(0)

__global__ __launch_bounds__(256, 2) void k_gemm_qkv_ws(
        const unsigned short* __restrict__ xs_hi,
        const unsigned short* __restrict__ xs_lo,
        const unsigned short* __restrict__ Whi,
        const unsigned short* __restrict__ Wlo,
        float* __restrict__ kT, float* __restrict__ vT, float* __restrict__ srT) {
    // [term][kg][col][8] — granule-linear so global_load_lds dest is
    // wave-uniform-base + lane*16; fragment reads are contiguous 16B granules.
    __shared__ __align__(16) short Bs[2][NKG][BN][8];   // 36,864 B

    const int tid  = threadIdx.x;
    const int lane = tid & 63;
    const int wid  = tid >> 6;          // 0..3
    const int l15  = lane & 15;
    const int lkg  = lane >> 4;         // 0..3
    const int kofs = lkg * 8;
    const int mat  = blockIdx.z;
    const int n0   = blockIdx.y * BN;

    const unsigned short* Wh = Whi + mat * (DIM * DIM);
    const unsigned short* Wl = Wlo + mat * (DIM * DIM);
    float* Out = (mat == 0) ? kT : (mat == 1 ? vT : srT);

    // ---- stage W slice (hi+lo) into LDS: 2304 granules, 9 rounds ----
    #pragma unroll
    for (int r = 0; r < 9; ++r) {
        int g  = r * 256 + tid;
        int g2 = (g >= 1152) ? g - 1152 : g;
        const unsigned short* src = (g >= 1152) ? Wl : Wh;
        int kg  = g2 / BN;
        int col = g2 - kg * BN;
        int doff = (r * 256 + wid * 64) * 16;   // wave-uniform base; HW adds lane*16
        gload16(src + (size_t)(n0 + col) * DIM + kg * 8, (char*)&Bs[0][0][0][0] + doff);
    }

    const int mbase = blockIdx.x * 256 + wid * 64;   // wave's 64 rows
    const int arow  = mbase + l15;

    f32x4 acc[4][3];
    #pragma unroll
    for (int i = 0; i < 4; ++i)
        #pragma unroll
        for (int j = 0; j < 3; ++j)
            acc[i][j] = (f32x4){0.f, 0.f, 0.f, 0.f};

    short8 ah0[4], al0[4], ah1[4], al1[4];
    short8 bh0[3], bl0[3], bh1[3], bl1[3];

    // A prefetch can start before the barrier (doesn't touch LDS)
    LOADA(ah0, al0, 0)
    LOADA(ah1, al1, 1)
    __syncthreads();                      // W staged (barrier drains vmcnt)

    LOADB(bh0, bl0, 0)
    LOADB(bh1, bl1, 1)
    FENCE;
    COMP(ah0, al0, bh0, bl0)              // chunk 0
    FENCE;
    LOADA(ah0, al0, 2)
    LOADB(bh0, bl0, 2)
    FENCE;
    COMP(ah1, al1, bh1, bl1)              // chunk 1
    FENCE;
    LOADA(ah1, al1, 3)
    LOADB(bh1, bl1, 3)
    FENCE;
    COMP(ah0, al0, bh0, bl0)              // chunk 2
    FENCE;
    LOADA(ah0, al0, 4)
    LOADB(bh0, bl0, 4)
    FENCE;
    COMP(ah1, al1, bh1, bl1)              // chunk 3
    FENCE;
    LOADA(ah1, al1, 5)
    LOADB(bh1, bl1, 5)
    FENCE;
    COMP(ah0, al0, bh0, bl0)              // chunk 4
    FENCE;
    COMP(ah1, al1, bh1, bl1)              // chunk 5

    const int b  = mbase >> 12;
    const int tb = (mbase & 4095) + lkg * 4;
    #pragma unroll
    for (int mf = 0; mf < 4; ++mf) {
        int t = tb + mf * 16;
        #pragma unroll
        for (int nf = 0; nf < 3; ++nf) {
            int c = n0 + nf * 16 + l15;
            f32x4 v = acc[mf][nf];
            if (mat == 2) {
                v.x = 1.0f / (1.0f + expf(-v.x));
                v.y = 1.0f / (1.0f + expf(-v.y));
                v.z = 1.0f / (1.0f + expf(-v.z));
                v.w = 1.0f / (1.0f + expf(-v.w));
            }
            *(f32x4*)&Out[((size_t)(b * DIM + c)) * NT + t] = v;
        }
    }
}

// ---------------------------------------------------------------------------
// Kernel 4: bidirectional WKV4 (unchanged). One block per (b,c).
__global__ __launch_bounds__(256) void k_wkv(
        const float* __restrict__ kT, const float* __restrict__ vT,
        const float* __restrict__ srT, const float* __restrict__ decay,
        const float* __restrict__ boost, float* __restrict__ zT) {
    __shared__ float sa[256], sb[256];
    int bc = blockIdx.x;
    int c = bc % DIM;
    size_t base = (size_t)bc * NT;
    int tid = threadIdx.x;
    int t0 = tid * 16;

    float w  = decay[c] * (1.0f / 4096.0f);
    float u  = boost[c] * (1.0f / 4096.0f);
    float ew = expf(-w);
    float eu = expf(u);

    float ek[16], ekv[16], vv[16];
    #pragma unroll
    for (int j = 0; j < 16; j += 4) {
        float4 k4 = *(const float4*)&kT[base + t0 + j];
        float4 v4 = *(const float4*)&vT[base + t0 + j];
        ek[j + 0] = expf(k4.x); ek[j + 1] = expf(k4.y);
        ek[j + 2] = expf(k4.z); ek[j + 3] = expf(k4.w);
        vv[j + 0] = v4.x; vv[j + 1] = v4.y; vv[j + 2] = v4.z; vv[j + 3] = v4.w;
        ekv[j + 0] = ek[j + 0] * v4.x; ekv[j + 1] = ek[j + 1] * v4.y;
        ekv[j + 2] = ek[j + 2] * v4.z; ekv[j + 3] = ek[j + 3] * v4.w;
    }

    float r = ew * ew; r = r * r; r = r * r; r = r * r;   // ew^16

    float La = 0.f, Lb = 0.f;
    #pragma unroll
    for (int j = 0; j < 16; ++j) { La = fmaf(ew, La, ekv[j]); Lb = fmaf(ew, Lb, ek[j]); }
    sa[tid] = La; sb[tid] = Lb;
    __syncthreads();
    float f = r;
    for (int d = 1; d < 256; d <<= 1) {
        float ta = (tid >= d) ? sa[tid - d] : 0.f;
        float tb_ = (tid >= d) ? sb[tid - d] : 0.f;
        __syncthreads();
        sa[tid] = fmaf(f, ta, sa[tid]);
        sb[tid] = fmaf(f, tb_, sb[tid]);
        __syncthreads();
        f = f * f;
    }
    float Ca = (tid > 0) ? sa[tid - 1] : 0.f;
    float Cb = (tid > 0) ? sb[tid - 1] : 0.f;
    __syncthreads();

    float Ra = 0.f, Rb = 0.f;
    #pragma unroll
    for (int j = 15; j >= 0; --j) { Ra = fmaf(ew, Ra, ekv[j]); Rb = fmaf(ew, Rb, ek[j]); }
    sa[255 - tid] = Ra; sb[255 - tid] = Rb;
    __syncthreads();
    f = r;
    for (int d = 1; d < 256; d <<= 1) {
        float ta = (tid >= d) ? sa[tid - d] : 0.f;
        float tb_ = (tid >= d) ? sb[tid - d] : 0.f;
        __syncthreads();
        sa[tid] = fmaf(f, ta, sa[tid]);
        sb[tid] = fmaf(f, tb_, sb[tid]);
        __syncthreads();
        f = f * f;
    }
    float Da = (tid < 255) ? sa[254 - tid] : 0.f;
    float Db = (tid < 255) ? sb[254 - tid] : 0.f;

    float ab[16], bb[16];
    {
        float a = Da, bv = Db;
        #pragma unroll
        for (int j = 15; j >= 0; --j) {
            ab[j] = a; bb[j] = bv;
            a  = fmaf(ew, a, ekv[j]);
            bv = fmaf(ew, bv, ek[j]);
        }
    }
    float outv[16];
    {
        float a = Ca, bv = Cb;
        #pragma unroll
        for (int j = 0; j < 16; ++j) {
            float af = a, bf = bv;
            a  = fmaf(ew, a, ekv[j]);
            bv = fmaf(ew, bv, ek[j]);
            float euk = eu * ek[j];
            float num = af + ab[j] + euk * vv[j];
            float den = bf + bb[j] + euk;
            outv[j] = num / den;
        }
    }
    #pragma unroll
    for (int j = 0; j < 16; j += 4) {
        float4 s4 = *(const float4*)&srT[base + t0 + j];
        float4 o;
        o.x = s4.x * outv[j + 0];
        o.y = s4.y * outv[j + 1];
        o.z = s4.z * outv[j + 2];
        o.w = s4.w * outv[j + 3];
        *(float4*)&zT[base + t0 + j] = o;
    }
}

// ---------------------------------------------------------------------------
// Kernel 5: output projection (fp32 VALU, unchanged). A = zT (B,C,T) k-major.
#define MT 128
#define NT_ 64
#define KT 32
#define LDA 132
#define LDB 68

__global__ __launch_bounds__(256) void k_gemm_out(
        const float* __restrict__ zT, const float* __restrict__ Wo,
        float* __restrict__ out) {
    __shared__ float As[KT][LDA];
    __shared__ float Bs2[KT][LDB];
    int tid = threadIdx.x;
    int m0 = blockIdx.x * MT;
    int n0 = blockIdx.y * NT_;
    int b  = m0 >> 12;
    int t0 = m0 & 4095;

    float acc[8][4];
    #pragma unroll
    for (int i = 0; i < 8; ++i)
        #pragma unroll
        for (int j = 0; j < 4; ++j) acc[i][j] = 0.f;

    int a_kk = tid >> 5;
    int a_c4 = (tid & 31) * 4;
    int b_n  = tid >> 3;
    int b_k4 = (tid & 7) * 4;
    int tmy = (tid >> 4) * 8;
    int tnx = (tid & 15) * 4;

    for (int k0 = 0; k0 < DIM; k0 += KT) {
        #pragma unroll
        for (int r = 0; r < 4; ++r) {
            int kk = a_kk + r * 8;
            float4 v = *(const float4*)&zT[((size_t)(b * DIM + k0 + kk)) * NT + t0 + a_c4];
            *(float4*)&As[kk][a_c4] = v;
        }
        #pragma unroll
        for (int r = 0; r < 2; ++r) {
            int nn = b_n + r * 32;
            float4 v = *(const float4*)&Wo[(size_t)(n0 + nn) * DIM + k0 + b_k4];
            Bs2[b_k4 + 0][nn] = v.x; Bs2[b_k4 + 1][nn] = v.y;
            Bs2[b_k4 + 2][nn] = v.z; Bs2[b_k4 + 3][nn] = v.w;
        }
        __syncthreads();
        #pragma unroll
        for (int kk = 0; kk < KT; ++kk) {
            float4 a0 = *(const float4*)&As[kk][tmy];
            float4 a1 = *(const float4*)&As[kk][tmy + 4];
            float4 b0 = *(const float4*)&Bs2[kk][tnx];
            float av[8] = {a0.x, a0.y, a0.z, a0.w, a1.x, a1.y, a1.z, a1.w};
            float bv[4] = {b0.x, b0.y, b0.z, b0.w};
            #pragma unroll
            for (int i = 0; i < 8; ++i)
                #pragma unroll
                for (int j = 0; j < 4; ++j)
                    acc[i][j] = fmaf(av[i], bv[j], acc[i][j]);
        }
        __syncthreads();
    }

    #pragma unroll
    for (int i = 0; i < 8; ++i) {
        size_t rowbase = (size_t)(m0 + tmy + i) * DIM + n0 + tnx;
        *(float4*)&out[rowbase] = make_float4(acc[i][0], acc[i][1], acc[i][2], acc[i][3]);
    }
}

// ---------------------------------------------------------------------------
extern "C" void kernel_launch(void* const* d_in, const int* in_sizes, int n_in,
                              void* d_out, int out_size, void* d_ws, size_t ws_size,
                              hipStream_t stream) {
    const float* x     = (const float*)d_in[0];
    const float* w1    = (const float*)d_in[1];
    const float* w3    = (const float*)d_in[2];
    const float* w5    = (const float*)d_in[3];
    const float* alpha = (const float*)d_in[4];
    const float* Wk    = (const float*)d_in[5];
    const float* Wv    = (const float*)d_in[6];
    const float* Wr    = (const float*)d_in[7];
    const float* Wo    = (const float*)d_in[8];
    const float* decay = (const float*)d_in[9];
    const float* boost = (const float*)d_in[10];
    float* out = (float*)d_out;
    float* ws  = (float*)d_ws;

    const size_t BIG = (size_t)NB * NT * DIM;   // 12,582,912 elements

    float* wc = ws;                                        // 4800 floats
    unsigned short* Whi = (unsigned short*)(ws + 8192);    // 110592 ushorts
    unsigned short* Wlo = (unsigned short*)(ws + 63488);   // 110592 ushorts
    unsigned short* xs_hi = (unsigned short*)(ws + 118784);   // BIG ushorts
    unsigned short* xs_lo = xs_hi + BIG;                      // BIG ushorts
    float* kT  = ws + 12701696;                               // BIG floats
    float* vT  = kT + BIG;
    float* srT = vT + BIG;
    float* zT  = ws + 118784;   // fp32, overlays xs_hi/xs_lo (dead after qkv)

    hipLaunchKernelGGL(k_prep, dim3(433), dim3(256), 0, stream,
                       w1, w3, w5, alpha, Wk, Wv, Wr, wc, Whi, Wlo);
    hipLaunchKernelGGL(k_conv, dim3(NB * NH), dim3(DIM), 0, stream,
                       x, wc, xs_hi, xs_lo);
    hipLaunchKernelGGL(k_gemm_qkv_ws, dim3(65536 / 256, DIM / BN, 3), dim3(256), 0, stream,
                       xs_hi, xs_lo, Whi, Wlo, kT, vT, srT);
    hipLaunchKernelGGL(k_wkv, dim3(NB * DIM), dim3(256), 0, stream,
                       kT, vT, srT, decay, boost, zT);
    hipLaunchKernelGGL(k_gemm_out, dim3(65536 / MT, DIM / NT_), dim3(256), 0, stream,
                       zT, Wo, out);
}